// Round 2
// baseline (1722.644 us; speedup 1.0000x reference)
//
#include <hip/hip_runtime.h>

typedef _Float16 half8 __attribute__((ext_vector_type(8)));
typedef _Float16 half4 __attribute__((ext_vector_type(4)));
typedef float f32x4 __attribute__((ext_vector_type(4)));

__device__ __forceinline__ void gload_lds16(const void* g, void* l) {
  __builtin_amdgcn_global_load_lds((const __attribute__((address_space(1))) void*)g,
                                   (__attribute__((address_space(3))) void*)l, 16, 0, 0);
}

// ---------------- BN partial sums: grid 128 = (seg<<4 | c) ----------------
__global__ __launch_bounds__(256) void k_bn_partial(const float* __restrict__ x,
                                                    float* __restrict__ part) {
  const int c = blockIdx.x & 15;
  const int seg = blockIdx.x >> 4;  // 0..7, 500 vertices each
  const int t = threadIdx.x;
  float s = 0.f, s2 = 0.f;
  for (int b = 0; b < 32; ++b) {
    const float* row = x + (size_t)(b * 16 + c) * 4000 + seg * 500;
    for (int v = t; v < 500; v += 256) {
      float val = row[v];
      s += val;
      s2 += val * val;
    }
  }
#pragma unroll
  for (int off = 32; off > 0; off >>= 1) {
    s += __shfl_down(s, off);
    s2 += __shfl_down(s2, off);
  }
  __shared__ float rs_[4], rs2_[4];
  if ((t & 63) == 0) { rs_[t >> 6] = s; rs2_[t >> 6] = s2; }
  __syncthreads();
  if (t == 0) {
    part[c * 8 + seg] = rs_[0] + rs_[1] + rs_[2] + rs_[3];
    part[128 + c * 8 + seg] = rs2_[0] + rs2_[1] + rs2_[2] + rs2_[3];
  }
}

// ---------------- BN finalize: musig[c]=mu, musig[16+c]=rstd ----------------
__global__ void k_bn_final(const float* __restrict__ part, float* __restrict__ musig) {
  const int c = threadIdx.x;
  if (c < 16) {
    float S = 0.f, S2 = 0.f;
#pragma unroll
    for (int seg = 0; seg < 8; ++seg) {
      S += part[c * 8 + seg];
      S2 += part[128 + c * 8 + seg];
    }
    const float inv = 1.f / 128000.f;
    float mu = S * inv;
    float var = S2 * inv - mu * mu;
    musig[c] = mu;
    musig[16 + c] = rsqrtf(var + 1e-5f);
  }
}

// ---------------- build x0 (normalized, permuted, transposed, scaled 1/16) ----------------
// X0[m*4096 + v] = x0[v][m],  m = c*32+b
__global__ __launch_bounds__(256) void k_build_x0(const float* __restrict__ x,
                                                  const int* __restrict__ perm,
                                                  const float* __restrict__ musig,
                                                  _Float16* __restrict__ X0) {
  const int idx = blockIdx.x * 256 + threadIdx.x;  // < 512*4096
  const int v = idx & 4095;
  const int m = idx >> 12;
  const int b = m & 31;
  const int c = m >> 5;
  const int pv = perm[v];
  float val = 0.f;
  if (pv < 4000)
    val = (x[((size_t)(b * 16 + c)) * 4000 + pv] - musig[c]) * musig[16 + c] * 0.0625f;
  X0[idx] = (_Float16)val;
}

// ---------------- f32 -> f16 convert ----------------
__global__ __launch_bounds__(256) void k_cvt_f16(const float* __restrict__ s,
                                                 _Float16* __restrict__ d, int n) {
  const int i = (blockIdx.x * 256 + threadIdx.x) * 4;
  if (i >= n) return;
  f32x4 v = *(const f32x4*)(s + i);
  half4 h;
  h[0] = (_Float16)v[0]; h[1] = (_Float16)v[1];
  h[2] = (_Float16)v[2]; h[3] = (_Float16)v[3];
  *(half4*)(d + i) = h;
}

// ---------------- W permute+pad: Wp[f][k*CS + c] = W[f][c*25 + k], k<25 else 0 ----------------
__global__ __launch_bounds__(256) void k_prep_w(const float* __restrict__ W,
                                                _Float16* __restrict__ Wp,
                                                int F, int shiftC) {
  const int idx = blockIdx.x * 256 + threadIdx.x;
  const int CS = 1 << shiftC;
  const int KPtot = 26 * CS;
  if (idx >= F * KPtot) return;
  const int f = idx / KPtot;
  const int rem = idx - f * KPtot;
  const int k = rem >> shiftC;
  const int c = rem & (CS - 1);
  float v = 0.f;
  if (k < 25) v = W[(size_t)f * (CS * 25) + c * 25 + k];
  Wp[idx] = (_Float16)v;
}

// ---------------- Chebyshev step GEMM ----------------
// Xout[m][v] = alpha*sum_u Xprev[m][u]*L[v][u] - beta*Xm2[m][v]
// Block tile 128(m) x 64(v), BK=64, 4 waves 2x2, wave tile 64x32 (4x2 frags).
// Staging: global_load_lds w=16, pre-swizzled global source, linear LDS dest,
// swizzled ds_read (byte ^ ((row&7)<<4)). Double-buffered, 1 barrier/iter.
__global__ __launch_bounds__(256, 1) void k_cheb(const _Float16* __restrict__ Xprev,
                                                 const _Float16* __restrict__ Lm,
                                                 const _Float16* __restrict__ Xm2,
                                                 _Float16* __restrict__ Xout,
                                                 int V, float alpha, float beta) {
  __shared__ _Float16 lds[2][12288];  // [buf][A: 128x64 | B: 64x64]
  const int t = threadIdx.x;
  const int lane = t & 63;
  const int w = t >> 6;
  const int wr = w >> 1, wc = w & 1;
  const int v0 = blockIdx.x * 64;
  const int m0 = blockIdx.y * 128;
  const size_t rs = (size_t)V * 2;  // row stride bytes

  const char* Ag = (const char*)Xprev + (size_t)m0 * rs;
  const char* Bg = (const char*)Lm + (size_t)v0 * rs;
  // per-lane source offset inside an 8-row group (inverse-swizzled)
  const size_t soff = (size_t)(lane >> 3) * rs + (size_t)(((lane & 7) * 16) ^ ((lane >> 3) << 4));

  f32x4 acc[4][2] = {};

  auto stage = [&](int buf, int tt) {
    const char* ag = Ag + (size_t)tt * 128 + soff;
    const char* bg = Bg + (size_t)tt * 128 + soff;
    char* A = (char*)&lds[buf][0];
    char* B = (char*)&lds[buf][8192];
#pragma unroll
    for (int j = 0; j < 4; ++j) {  // A rows w*32 .. w*32+31
      const int r0 = w * 32 + j * 8;
      gload_lds16(ag + (size_t)r0 * rs, A + r0 * 128);
    }
#pragma unroll
    for (int j = 0; j < 2; ++j) {  // B rows w*16 .. w*16+15
      const int r0 = w * 16 + j * 8;
      gload_lds16(bg + (size_t)r0 * rs, B + r0 * 128);
    }
  };

  stage(0, 0);
  __syncthreads();

  const int NT = V >> 6;
  for (int tt = 0; tt < NT; ++tt) {
    const int cur = tt & 1;
    if (tt + 1 < NT) stage(cur ^ 1, tt + 1);
    const char* A = (const char*)&lds[cur][0];
    const char* B = (const char*)&lds[cur][8192];
#pragma unroll
    for (int kk = 0; kk < 2; ++kk) {
      const int cb = kk * 64 + ((lane >> 4) << 4);
      half8 a[4], b[2];
#pragma unroll
      for (int mi = 0; mi < 4; ++mi) {
        const int ar = wr * 64 + mi * 16 + (lane & 15);
        a[mi] = *(const half8*)(A + ar * 128 + (cb ^ ((ar & 7) << 4)));
      }
#pragma unroll
      for (int ni = 0; ni < 2; ++ni) {
        const int br = wc * 32 + ni * 16 + (lane & 15);
        b[ni] = *(const half8*)(B + br * 128 + (cb ^ ((br & 7) << 4)));
      }
#pragma unroll
      for (int mi = 0; mi < 4; ++mi)
#pragma unroll
        for (int ni = 0; ni < 2; ++ni)
          acc[mi][ni] = __builtin_amdgcn_mfma_f32_16x16x32_f16(a[mi], b[ni], acc[mi][ni], 0, 0, 0);
    }
    __syncthreads();
  }

  // epilogue: xk = alpha*acc - beta*xm2, store f16
  const int rbase = (lane >> 4) << 2;
#pragma unroll
  for (int mi = 0; mi < 4; ++mi) {
#pragma unroll
    for (int ni = 0; ni < 2; ++ni) {
      const int vv = v0 + wc * 32 + ni * 16 + (lane & 15);
#pragma unroll
      for (int r = 0; r < 4; ++r) {
        const int mm = m0 + wr * 64 + mi * 16 + rbase + r;
        const size_t idx = (size_t)mm * V + vv;
        float val = alpha * acc[mi][ni][r];
        if (beta != 0.f) val -= (float)Xm2[idx];
        Xout[idx] = (_Float16)val;
      }
    }
  }
}

// ---------------- Dense projection GEMM (64f x 64n tile), fused bias+relu ----------------
// Yt[f][n] = relu(ascale * sum_q Wp[f][q] * B[q][n] + bscale*bias[f]),
// B[q][n] = XS[k][c*32+b][v], q = k<<shiftC | c, n = b*Vv + v
__global__ __launch_bounds__(256, 2) void k_dense(const _Float16* __restrict__ Wp,
                                                  const _Float16* __restrict__ XS,
                                                  const float* __restrict__ bias,
                                                  float* __restrict__ Yt,
                                                  int Vv, int shiftC, int nsteps,
                                                  size_t planeV, int Ntot,
                                                  float ascale, float bscale) {
  __shared__ _Float16 Alds[64 * 32];
  __shared__ _Float16 Blds[32 * 64];
  const int t = threadIdx.x;
  const int lane = t & 63;
  const int w = t >> 6;
  const int n0 = blockIdx.x * 64;
  const int f0 = blockIdx.y * 64;
  const int b = n0 / Vv;
  const int vb = n0 % Vv;
  const int KP = nsteps * 32;
  const int cmask = (1 << shiftC) - 1;

  f32x4 acc0 = {0.f, 0.f, 0.f, 0.f}, acc1 = {0.f, 0.f, 0.f, 0.f};
  f32x4 acc2 = {0.f, 0.f, 0.f, 0.f}, acc3 = {0.f, 0.f, 0.f, 0.f};

  for (int s = 0; s < nsteps; ++s) {
    const int q0 = s * 32;
    {  // A stage: 64 rows x 64B
      const int row = t >> 2, cb = (t & 3) * 16;
      half8 v = *(const half8*)((const char*)Wp + ((size_t)(f0 + row) * KP + q0) * 2 + cb);
      *(half8*)((char*)Alds + row * 64 + cb) = v;
    }
    {  // B stage: 32 rows x 128B, zero-pad k>=25
      const int q = q0 + (t >> 3), cb = (t & 7) * 16;
      const int k = q >> shiftC, c = q & cmask;
      half8 v = {};
      if (k < 25)
        v = *(const half8*)((const char*)XS +
                            ((size_t)k * planeV + (size_t)(c * 32 + b) * Vv + vb) * 2 + cb);
      *(half8*)((char*)Blds + (t >> 3) * 128 + cb) = v;
    }
    __syncthreads();
    half8 a0 = *(const half8*)((char*)Alds + ((lane & 15) + 0) * 64 + ((lane >> 4) << 4));
    half8 a1 = *(const half8*)((char*)Alds + ((lane & 15) + 16) * 64 + ((lane >> 4) << 4));
    half8 a2 = *(const half8*)((char*)Alds + ((lane & 15) + 32) * 64 + ((lane >> 4) << 4));
    half8 a3 = *(const half8*)((char*)Alds + ((lane & 15) + 48) * 64 + ((lane >> 4) << 4));
    half8 bf;
    const int col = (w << 4) + (lane & 15);
#pragma unroll
    for (int j = 0; j < 8; ++j)
      bf[j] = Blds[(((lane >> 4) << 3) + j) * 64 + col];
    acc0 = __builtin_amdgcn_mfma_f32_16x16x32_f16(a0, bf, acc0, 0, 0, 0);
    acc1 = __builtin_amdgcn_mfma_f32_16x16x32_f16(a1, bf, acc1, 0, 0, 0);
    acc2 = __builtin_amdgcn_mfma_f32_16x16x32_f16(a2, bf, acc2, 0, 0, 0);
    acc3 = __builtin_amdgcn_mfma_f32_16x16x32_f16(a3, bf, acc3, 0, 0, 0);
    __syncthreads();
  }

  const int n = n0 + (w << 4) + (lane & 15);
  f32x4 accs[4] = {acc0, acc1, acc2, acc3};
#pragma unroll
  for (int mi = 0; mi < 4; ++mi) {
#pragma unroll
    for (int r = 0; r < 4; ++r) {
      const int f = f0 + (mi << 4) + ((lane >> 4) << 2) + r;
      float val = ascale * accs[mi][r] + bscale * bias[f];
      Yt[(size_t)f * Ntot + n] = fmaxf(val, 0.f);
    }
  }
}

// ---------------- pool1: Yt1(64 x 131072) -> XS plane0 (2048 x 1024), scale 1/64 ----------------
__global__ __launch_bounds__(256) void k_pool1(const float* __restrict__ Yt,
                                               _Float16* __restrict__ X2) {
  const int idx = blockIdx.x * 256 + threadIdx.x;  // < 64*32*1024
  const int v2 = idx & 1023;
  const int rest = idx >> 10;
  const int b = rest & 31;
  const int f = rest >> 5;
  f32x4 q = *(const f32x4*)(Yt + (size_t)f * 131072 + b * 4096 + v2 * 4);
  float mx = fmaxf(fmaxf(q[0], q[1]), fmaxf(q[2], q[3]));
  X2[(size_t)(f * 32 + b) * 1024 + v2] = (_Float16)(mx * 0.015625f);
}

// ---------------- pool2: Yt2(128 x 32768) -> p2[b][f][v3] (32 x 128 x 256) ----------------
__global__ __launch_bounds__(256) void k_pool2(const float* __restrict__ Yt,
                                               float* __restrict__ p2) {
  const int idx = blockIdx.x * 256 + threadIdx.x;  // < 32*128*256
  const int v3 = idx & 255;
  const int rest = idx >> 8;
  const int f = rest & 127;
  const int b = rest >> 7;
  f32x4 q = *(const f32x4*)(Yt + (size_t)f * 32768 + b * 1024 + v3 * 4);
  float mx = fmaxf(fmaxf(q[0], q[1]), fmaxf(q[2], q[3]));
  p2[(size_t)b * 32768 + f * 256 + v3] = mx;
}

// ---------------- FC: out[b][o] = 64 * sum_i p2[b][i]*Wfc[o][i] + bfc[o] ----------------
__global__ __launch_bounds__(256) void k_fc(const float* __restrict__ p2,
                                            const float* __restrict__ Wfc,
                                            const float* __restrict__ bfc,
                                            float* __restrict__ out) {
  const int b = blockIdx.x;
  const int t = threadIdx.x;
  float acc[10];
#pragma unroll
  for (int o = 0; o < 10; ++o) acc[o] = 0.f;
  const float* pb = p2 + (size_t)b * 32768;
  for (int i = t; i < 32768; i += 256) {
    float p = pb[i];
#pragma unroll
    for (int o = 0; o < 10; ++o) acc[o] += p * Wfc[(size_t)o * 32768 + i];
  }
  __shared__ float red[10][256];
#pragma unroll
  for (int o = 0; o < 10; ++o) red[o][t] = acc[o];
  __syncthreads();
  for (int s = 128; s > 0; s >>= 1) {
    if (t < s) {
#pragma unroll
      for (int o = 0; o < 10; ++o) red[o][t] += red[o][t + s];
    }
    __syncthreads();
  }
  if (t < 10) out[b * 10 + t] = 64.f * red[t][0] + bfc[t];
}

extern "C" void kernel_launch(void* const* d_in, const int* in_sizes, int n_in,
                              void* d_out, int out_size, void* d_ws, size_t ws_size,
                              hipStream_t stream) {
  (void)in_sizes; (void)n_in; (void)out_size; (void)ws_size;
  const float* x = (const float*)d_in[0];
  const int* perm = (const int*)d_in[1];
  const float* L1 = (const float*)d_in[2];
  const float* L2 = (const float*)d_in[3];
  const float* W1 = (const float*)d_in[4];
  const float* b1 = (const float*)d_in[5];
  const float* W2 = (const float*)d_in[6];
  const float* b2 = (const float*)d_in[7];
  const float* Wfc = (const float*)d_in[8];
  const float* bfc = (const float*)d_in[9];
  float* out = (float*)d_out;

  char* ws = (char*)d_ws;
  size_t off = 0;
  auto alloc = [&](size_t bytes) {
    char* p = ws + off;
    off += (bytes + 255) & ~(size_t)255;
    return p;
  };
  _Float16* L1h = (_Float16*)alloc(16777216ull * 2);
  _Float16* L2h = (_Float16*)alloc(1048576ull * 2);
  _Float16* W1p = (_Float16*)alloc(64ull * 416 * 2);
  _Float16* W2p = (_Float16*)alloc(128ull * 1664 * 2);
  float* part = (float*)alloc(256 * 4);
  float* musig = (float*)alloc(32 * 4);
  _Float16* XS = (_Float16*)alloc(25ull * 2097152 * 2);   // states, reused conv1/conv2
  float* Yt = (float*)alloc(64ull * 131072 * 4);          // reused for Yt2
  float* p2 = (float*)alloc(32ull * 128 * 256 * 4);

  k_cvt_f16<<<16384, 256, 0, stream>>>(L1, L1h, 16777216);
  k_cvt_f16<<<1024, 256, 0, stream>>>(L2, L2h, 1048576);
  k_prep_w<<<104, 256, 0, stream>>>(W1, W1p, 64, 4);
  k_prep_w<<<832, 256, 0, stream>>>(W2, W2p, 128, 6);
  k_bn_partial<<<128, 256, 0, stream>>>(x, part);
  k_bn_final<<<1, 64, 0, stream>>>(part, musig);
  k_build_x0<<<8192, 256, 0, stream>>>(x, perm, musig, XS);

  const size_t plane = 2097152;
  for (int k = 1; k < 25; ++k) {
    k_cheb<<<dim3(64, 4), 256, 0, stream>>>(
        XS + (size_t)(k - 1) * plane, L1h,
        XS + (size_t)(k >= 2 ? k - 2 : 0) * plane, XS + (size_t)k * plane,
        4096, (k == 1) ? 1.f : 2.f, (k == 1) ? 0.f : 1.f);
  }
  k_dense<<<dim3(2048, 1), 256, 0, stream>>>(W1p, XS, b1, Yt, 4096, 4, 13, plane,
                                             131072, 16.f, 1.f);
  k_pool1<<<8192, 256, 0, stream>>>(Yt, XS);
  for (int k = 1; k < 25; ++k) {
    k_cheb<<<dim3(16, 16), 256, 0, stream>>>(
        XS + (size_t)(k - 1) * plane, L2h,
        XS + (size_t)(k >= 2 ? k - 2 : 0) * plane, XS + (size_t)k * plane,
        1024, (k == 1) ? 1.f : 2.f, (k == 1) ? 0.f : 1.f);
  }
  k_dense<<<dim3(512, 2), 256, 0, stream>>>(W2p, XS, b2, Yt, 1024, 6, 52, plane,
                                            32768, 1.f, 0.015625f);
  k_pool2<<<4096, 256, 0, stream>>>(Yt, p2);
  k_fc<<<32, 256, 0, stream>>>(p2, Wfc, bfc, out);
}

// Round 3
// 1292.634 us; speedup vs baseline: 1.3327x; 1.3327x over previous
//
#include <hip/hip_runtime.h>

typedef _Float16 half8 __attribute__((ext_vector_type(8)));
typedef _Float16 half4 __attribute__((ext_vector_type(4)));
typedef float f32x4 __attribute__((ext_vector_type(4)));

__device__ __forceinline__ void gload_lds16(const void* g, void* l) {
  __builtin_amdgcn_global_load_lds((const __attribute__((address_space(1))) void*)g,
                                   (__attribute__((address_space(3))) void*)l, 16, 0, 0);
}

// ---------------- BN partial sums: grid 128 = (seg<<4 | c) ----------------
__global__ __launch_bounds__(256) void k_bn_partial(const float* __restrict__ x,
                                                    float* __restrict__ part) {
  const int c = blockIdx.x & 15;
  const int seg = blockIdx.x >> 4;  // 0..7, 500 vertices each
  const int t = threadIdx.x;
  float s = 0.f, s2 = 0.f;
  for (int b = 0; b < 32; ++b) {
    const float* row = x + (size_t)(b * 16 + c) * 4000 + seg * 500;
    for (int v = t; v < 500; v += 256) {
      float val = row[v];
      s += val;
      s2 += val * val;
    }
  }
#pragma unroll
  for (int off = 32; off > 0; off >>= 1) {
    s += __shfl_down(s, off);
    s2 += __shfl_down(s2, off);
  }
  __shared__ float rs_[4], rs2_[4];
  if ((t & 63) == 0) { rs_[t >> 6] = s; rs2_[t >> 6] = s2; }
  __syncthreads();
  if (t == 0) {
    part[c * 8 + seg] = rs_[0] + rs_[1] + rs_[2] + rs_[3];
    part[128 + c * 8 + seg] = rs2_[0] + rs2_[1] + rs2_[2] + rs2_[3];
  }
}

// ---------------- BN finalize: musig[c]=mu, musig[16+c]=rstd ----------------
__global__ void k_bn_final(const float* __restrict__ part, float* __restrict__ musig) {
  const int c = threadIdx.x;
  if (c < 16) {
    float S = 0.f, S2 = 0.f;
#pragma unroll
    for (int seg = 0; seg < 8; ++seg) {
      S += part[c * 8 + seg];
      S2 += part[128 + c * 8 + seg];
    }
    const float inv = 1.f / 128000.f;
    float mu = S * inv;
    float var = S2 * inv - mu * mu;
    musig[c] = mu;
    musig[16 + c] = rsqrtf(var + 1e-5f);
  }
}

// ---------------- build x0 (normalized, permuted, transposed, scaled 1/16) ----------------
// X0[m*4096 + v] = x0[v][m],  m = c*32+b
__global__ __launch_bounds__(256) void k_build_x0(const float* __restrict__ x,
                                                  const int* __restrict__ perm,
                                                  const float* __restrict__ musig,
                                                  _Float16* __restrict__ X0) {
  const int idx = blockIdx.x * 256 + threadIdx.x;  // < 512*4096
  const int v = idx & 4095;
  const int m = idx >> 12;
  const int b = m & 31;
  const int c = m >> 5;
  const int pv = perm[v];
  float val = 0.f;
  if (pv < 4000)
    val = (x[((size_t)(b * 16 + c)) * 4000 + pv] - musig[c]) * musig[16 + c] * 0.0625f;
  X0[idx] = (_Float16)val;
}

// ---------------- f32 -> f16 convert ----------------
__global__ __launch_bounds__(256) void k_cvt_f16(const float* __restrict__ s,
                                                 _Float16* __restrict__ d, int n) {
  const int i = (blockIdx.x * 256 + threadIdx.x) * 4;
  if (i >= n) return;
  f32x4 v = *(const f32x4*)(s + i);
  half4 h;
  h[0] = (_Float16)v[0]; h[1] = (_Float16)v[1];
  h[2] = (_Float16)v[2]; h[3] = (_Float16)v[3];
  *(half4*)(d + i) = h;
}

// ---------------- W permute+pad: Wp[f][k*CS + c] = W[f][c*25 + k], k<25 else 0 ----------------
__global__ __launch_bounds__(256) void k_prep_w(const float* __restrict__ W,
                                                _Float16* __restrict__ Wp,
                                                int F, int shiftC) {
  const int idx = blockIdx.x * 256 + threadIdx.x;
  const int CS = 1 << shiftC;
  const int KPtot = 26 * CS;
  if (idx >= F * KPtot) return;
  const int f = idx / KPtot;
  const int rem = idx - f * KPtot;
  const int k = rem >> shiftC;
  const int c = rem & (CS - 1);
  float v = 0.f;
  if (k < 25) v = W[(size_t)f * (CS * 25) + c * 25 + k];
  Wp[idx] = (_Float16)v;
}

// ---------------- Chebyshev step GEMM ----------------
// Xout[m][v] = alpha*sum_u Xprev[m][u]*L[v][u] - beta*Xm2[m][v]
// Block 128(m) x 64(v), 512 threads = 8 waves: 2x2 spatial quadrants x 2 K-halves.
// Each K-half: independent dbuf LDS pipeline (24KB/buf), gload_lds w=16 staging
// (pre-swizzled source, linear dest), counted vmcnt(6) + raw barriers (no drain).
// Cross-half f32 reduction through LDS at the end.
__global__ __launch_bounds__(512, 2) void k_cheb(const _Float16* __restrict__ Xprev,
                                                 const _Float16* __restrict__ Lm,
                                                 const _Float16* __restrict__ Xm2,
                                                 _Float16* __restrict__ Xout,
                                                 int V, float alpha, float beta) {
  __shared__ _Float16 lds[2][2][12288];  // [kh][buf][A:128x64 | B:64x64]
  const int t = threadIdx.x;
  const int lane = t & 63;
  const int w = t >> 6;
  const int kh = w >> 2;          // K-half
  const int wl = w & 3;           // wave-in-half
  const int wr = wl >> 1, wc = wl & 1;
  const int v0 = blockIdx.x * 64;
  const int m0 = blockIdx.y * 128;
  const size_t rs = (size_t)V * 2;  // row stride bytes
  const int K2 = V >> 1;
  const int NT2 = K2 >> 6;

  const char* Ag = (const char*)Xprev + (size_t)m0 * rs + (size_t)kh * K2 * 2;
  const char* Bg = (const char*)Lm + (size_t)v0 * rs + (size_t)kh * K2 * 2;
  // per-lane source offset within an 8-row group (inverse-swizzled)
  const size_t soff = (size_t)(lane >> 3) * rs + (size_t)(((lane & 7) * 16) ^ ((lane >> 3) << 4));

  f32x4 acc[4][2] = {};

  auto stage = [&](int buf, int tt) {  // 6 gload_lds per wave
    const char* ag = Ag + (size_t)tt * 128 + soff;
    const char* bg = Bg + (size_t)tt * 128 + soff;
    char* A = (char*)&lds[kh][buf][0];
    char* B = (char*)&lds[kh][buf][8192];
#pragma unroll
    for (int j = 0; j < 4; ++j) {  // A rows wl*32 .. +31
      const int r0 = wl * 32 + j * 8;
      gload_lds16(ag + (size_t)r0 * rs, A + r0 * 128);
    }
#pragma unroll
    for (int j = 0; j < 2; ++j) {  // B rows wl*16 .. +15
      const int r0 = wl * 16 + j * 8;
      gload_lds16(bg + (size_t)r0 * rs, B + r0 * 128);
    }
  };

  stage(0, 0);

  for (int tt = 0; tt < NT2; ++tt) {
    const int cur = tt & 1;
    if (tt + 1 < NT2) {
      stage(cur ^ 1, tt + 1);
      asm volatile("s_waitcnt vmcnt(6)" ::: "memory");  // own stage(tt) landed
    } else {
      asm volatile("s_waitcnt vmcnt(0)" ::: "memory");
    }
    asm volatile("s_barrier" ::: "memory");  // all waves' stage(tt) landed
    const char* A = (const char*)&lds[kh][cur][0];
    const char* B = (const char*)&lds[kh][cur][8192];
#pragma unroll
    for (int kk = 0; kk < 2; ++kk) {
      const int cb = kk * 64 + ((lane >> 4) << 4);
      half8 a[4], b[2];
#pragma unroll
      for (int mi = 0; mi < 4; ++mi) {
        const int ar = wr * 64 + mi * 16 + (lane & 15);
        a[mi] = *(const half8*)(A + ar * 128 + (cb ^ ((ar & 7) << 4)));
      }
#pragma unroll
      for (int ni = 0; ni < 2; ++ni) {
        const int br = wc * 32 + ni * 16 + (lane & 15);
        b[ni] = *(const half8*)(B + br * 128 + (cb ^ ((br & 7) << 4)));
      }
#pragma unroll
      for (int mi = 0; mi < 4; ++mi)
#pragma unroll
        for (int ni = 0; ni < 2; ++ni)
          acc[mi][ni] = __builtin_amdgcn_mfma_f32_16x16x32_f16(a[mi], b[ni], acc[mi][ni], 0, 0, 0);
    }
    asm volatile("s_barrier" ::: "memory");  // reads of cur done before restage
  }

  // ---- cross-half reduction (f32 via LDS) + epilogue ----
  __syncthreads();
  float* red = (float*)&lds[0][0][0];  // 32KB scratch
  if (kh == 1) {
    float* dst = red + wl * 2048 + lane * 4;
#pragma unroll
    for (int mi = 0; mi < 4; ++mi)
#pragma unroll
      for (int ni = 0; ni < 2; ++ni)
        *(f32x4*)(dst + (mi * 2 + ni) * 256) = acc[mi][ni];
  }
  __syncthreads();
  if (kh == 0) {
    const float* src = red + wl * 2048 + lane * 4;
    const int rbase = (lane >> 4) << 2;
#pragma unroll
    for (int mi = 0; mi < 4; ++mi) {
#pragma unroll
      for (int ni = 0; ni < 2; ++ni) {
        f32x4 o = *(const f32x4*)(src + (mi * 2 + ni) * 256);
        const int vv = v0 + wc * 32 + ni * 16 + (lane & 15);
#pragma unroll
        for (int r = 0; r < 4; ++r) {
          const int mm = m0 + wr * 64 + mi * 16 + rbase + r;
          const size_t idx = (size_t)mm * V + vv;
          float val = alpha * (acc[mi][ni][r] + o[r]);
          if (beta != 0.f) val -= (float)Xm2[idx];
          Xout[idx] = (_Float16)val;
        }
      }
    }
  }
}

// ---------------- Dense projection GEMM (64f x 64n tile), fused bias+relu ----------------
// Yt[f][n] = relu(ascale * sum_q Wp[f][q] * B[q][n] + bscale*bias[f]),
// B[q][n] = XS[k][c*32+b][v], q = k<<shiftC | c, n = b*Vv + v
__global__ __launch_bounds__(256, 2) void k_dense(const _Float16* __restrict__ Wp,
                                                  const _Float16* __restrict__ XS,
                                                  const float* __restrict__ bias,
                                                  float* __restrict__ Yt,
                                                  int Vv, int shiftC, int nsteps,
                                                  size_t planeV, int Ntot,
                                                  float ascale, float bscale) {
  __shared__ _Float16 Alds[64 * 32];
  __shared__ _Float16 Blds[32 * 64];
  const int t = threadIdx.x;
  const int lane = t & 63;
  const int w = t >> 6;
  const int n0 = blockIdx.x * 64;
  const int f0 = blockIdx.y * 64;
  const int b = n0 / Vv;
  const int vb = n0 % Vv;
  const int KP = nsteps * 32;
  const int cmask = (1 << shiftC) - 1;

  f32x4 acc0 = {0.f, 0.f, 0.f, 0.f}, acc1 = {0.f, 0.f, 0.f, 0.f};
  f32x4 acc2 = {0.f, 0.f, 0.f, 0.f}, acc3 = {0.f, 0.f, 0.f, 0.f};

  for (int s = 0; s < nsteps; ++s) {
    const int q0 = s * 32;
    {  // A stage: 64 rows x 64B
      const int row = t >> 2, cb = (t & 3) * 16;
      half8 v = *(const half8*)((const char*)Wp + ((size_t)(f0 + row) * KP + q0) * 2 + cb);
      *(half8*)((char*)Alds + row * 64 + cb) = v;
    }
    {  // B stage: 32 rows x 128B, zero-pad k>=25
      const int q = q0 + (t >> 3), cb = (t & 7) * 16;
      const int k = q >> shiftC, c = q & cmask;
      half8 v = {};
      if (k < 25)
        v = *(const half8*)((const char*)XS +
                            ((size_t)k * planeV + (size_t)(c * 32 + b) * Vv + vb) * 2 + cb);
      *(half8*)((char*)Blds + (t >> 3) * 128 + cb) = v;
    }
    __syncthreads();
    half8 a0 = *(const half8*)((char*)Alds + ((lane & 15) + 0) * 64 + ((lane >> 4) << 4));
    half8 a1 = *(const half8*)((char*)Alds + ((lane & 15) + 16) * 64 + ((lane >> 4) << 4));
    half8 a2 = *(const half8*)((char*)Alds + ((lane & 15) + 32) * 64 + ((lane >> 4) << 4));
    half8 a3 = *(const half8*)((char*)Alds + ((lane & 15) + 48) * 64 + ((lane >> 4) << 4));
    half8 bf;
    const int col = (w << 4) + (lane & 15);
#pragma unroll
    for (int j = 0; j < 8; ++j)
      bf[j] = Blds[(((lane >> 4) << 3) + j) * 64 + col];
    acc0 = __builtin_amdgcn_mfma_f32_16x16x32_f16(a0, bf, acc0, 0, 0, 0);
    acc1 = __builtin_amdgcn_mfma_f32_16x16x32_f16(a1, bf, acc1, 0, 0, 0);
    acc2 = __builtin_amdgcn_mfma_f32_16x16x32_f16(a2, bf, acc2, 0, 0, 0);
    acc3 = __builtin_amdgcn_mfma_f32_16x16x32_f16(a3, bf, acc3, 0, 0, 0);
    __syncthreads();
  }

  const int n = n0 + (w << 4) + (lane & 15);
  f32x4 accs[4] = {acc0, acc1, acc2, acc3};
#pragma unroll
  for (int mi = 0; mi < 4; ++mi) {
#pragma unroll
    for (int r = 0; r < 4; ++r) {
      const int f = f0 + (mi << 4) + ((lane >> 4) << 2) + r;
      float val = ascale * accs[mi][r] + bscale * bias[f];
      Yt[(size_t)f * Ntot + n] = fmaxf(val, 0.f);
    }
  }
}

// ---------------- pool1: Yt1(64 x 131072) -> XS plane0 (2048 x 1024), scale 1/64 ----------------
__global__ __launch_bounds__(256) void k_pool1(const float* __restrict__ Yt,
                                               _Float16* __restrict__ X2) {
  const int idx = blockIdx.x * 256 + threadIdx.x;  // < 64*32*1024
  const int v2 = idx & 1023;
  const int rest = idx >> 10;
  const int b = rest & 31;
  const int f = rest >> 5;
  f32x4 q = *(const f32x4*)(Yt + (size_t)f * 131072 + b * 4096 + v2 * 4);
  float mx = fmaxf(fmaxf(q[0], q[1]), fmaxf(q[2], q[3]));
  X2[(size_t)(f * 32 + b) * 1024 + v2] = (_Float16)(mx * 0.015625f);
}

// ---------------- pool2: Yt2(128 x 32768) -> p2[b][f][v3] (32 x 128 x 256) ----------------
__global__ __launch_bounds__(256) void k_pool2(const float* __restrict__ Yt,
                                               float* __restrict__ p2) {
  const int idx = blockIdx.x * 256 + threadIdx.x;  // < 32*128*256
  const int v3 = idx & 255;
  const int rest = idx >> 8;
  const int f = rest & 127;
  const int b = rest >> 7;
  f32x4 q = *(const f32x4*)(Yt + (size_t)f * 32768 + b * 1024 + v3 * 4);
  float mx = fmaxf(fmaxf(q[0], q[1]), fmaxf(q[2], q[3]));
  p2[(size_t)b * 32768 + f * 256 + v3] = mx;
}

// ---------------- FC pass 1: partial GEMV, grid 256 = (b<<3 | seg) ----------------
__global__ __launch_bounds__(256) void k_fc_part(const float* __restrict__ p2,
                                                 const float* __restrict__ Wfc,
                                                 float* __restrict__ partF) {
  const int b = blockIdx.x >> 3;
  const int seg = blockIdx.x & 7;  // 4096 i's per seg
  const int t = threadIdx.x;
  const int lane = t & 63;
  const int w = t >> 6;
  const int base = seg * 4096;
  float acc[10];
#pragma unroll
  for (int o = 0; o < 10; ++o) acc[o] = 0.f;
  const float* pb = p2 + (size_t)b * 32768 + base;
  for (int i = t; i < 4096; i += 256) {
    float p = pb[i];
#pragma unroll
    for (int o = 0; o < 10; ++o) acc[o] += p * Wfc[(size_t)o * 32768 + base + i];
  }
#pragma unroll
  for (int off = 32; off > 0; off >>= 1)
#pragma unroll
    for (int o = 0; o < 10; ++o) acc[o] += __shfl_down(acc[o], off);
  __shared__ float rws[10][4];
  if (lane == 0) {
#pragma unroll
    for (int o = 0; o < 10; ++o) rws[o][w] = acc[o];
  }
  __syncthreads();
  if (t < 10) partF[blockIdx.x * 10 + t] =
      rws[t][0] + rws[t][1] + rws[t][2] + rws[t][3];
}

// ---------------- FC pass 2: out[b][o] = 64 * sum_seg part + bfc[o] ----------------
__global__ void k_fc_final(const float* __restrict__ partF,
                           const float* __restrict__ bfc,
                           float* __restrict__ out) {
  const int t = threadIdx.x;
  if (t < 320) {
    const int b = t / 10, o = t - b * 10;
    float s = 0.f;
#pragma unroll
    for (int seg = 0; seg < 8; ++seg) s += partF[(b * 8 + seg) * 10 + o];
    out[b * 10 + o] = 64.f * s + bfc[o];
  }
}

extern "C" void kernel_launch(void* const* d_in, const int* in_sizes, int n_in,
                              void* d_out, int out_size, void* d_ws, size_t ws_size,
                              hipStream_t stream) {
  (void)in_sizes; (void)n_in; (void)out_size; (void)ws_size;
  const float* x = (const float*)d_in[0];
  const int* perm = (const int*)d_in[1];
  const float* L1 = (const float*)d_in[2];
  const float* L2 = (const float*)d_in[3];
  const float* W1 = (const float*)d_in[4];
  const float* b1 = (const float*)d_in[5];
  const float* W2 = (const float*)d_in[6];
  const float* b2 = (const float*)d_in[7];
  const float* Wfc = (const float*)d_in[8];
  const float* bfc = (const float*)d_in[9];
  float* out = (float*)d_out;

  char* ws = (char*)d_ws;
  size_t off = 0;
  auto alloc = [&](size_t bytes) {
    char* p = ws + off;
    off += (bytes + 255) & ~(size_t)255;
    return p;
  };
  _Float16* L1h = (_Float16*)alloc(16777216ull * 2);
  _Float16* L2h = (_Float16*)alloc(1048576ull * 2);
  _Float16* W1p = (_Float16*)alloc(64ull * 416 * 2);
  _Float16* W2p = (_Float16*)alloc(128ull * 1664 * 2);
  float* part = (float*)alloc(256 * 4);
  float* musig = (float*)alloc(32 * 4);
  float* partF = (float*)alloc(2560 * 4);
  _Float16* XS = (_Float16*)alloc(25ull * 2097152 * 2);   // states, reused conv1/conv2
  float* Yt = (float*)alloc(64ull * 131072 * 4);          // reused for Yt2
  float* p2 = (float*)alloc(32ull * 128 * 256 * 4);

  k_cvt_f16<<<16384, 256, 0, stream>>>(L1, L1h, 16777216);
  k_cvt_f16<<<1024, 256, 0, stream>>>(L2, L2h, 1048576);
  k_prep_w<<<104, 256, 0, stream>>>(W1, W1p, 64, 4);
  k_prep_w<<<832, 256, 0, stream>>>(W2, W2p, 128, 6);
  k_bn_partial<<<128, 256, 0, stream>>>(x, part);
  k_bn_final<<<1, 64, 0, stream>>>(part, musig);
  k_build_x0<<<8192, 256, 0, stream>>>(x, perm, musig, XS);

  const size_t plane = 2097152;
  for (int k = 1; k < 25; ++k) {
    k_cheb<<<dim3(64, 4), 512, 0, stream>>>(
        XS + (size_t)(k - 1) * plane, L1h,
        XS + (size_t)(k >= 2 ? k - 2 : 0) * plane, XS + (size_t)k * plane,
        4096, (k == 1) ? 1.f : 2.f, (k == 1) ? 0.f : 1.f);
  }
  k_dense<<<dim3(2048, 1), 256, 0, stream>>>(W1p, XS, b1, Yt, 4096, 4, 13, plane,
                                             131072, 16.f, 1.f);
  k_pool1<<<8192, 256, 0, stream>>>(Yt, XS);
  for (int k = 1; k < 25; ++k) {
    k_cheb<<<dim3(16, 16), 512, 0, stream>>>(
        XS + (size_t)(k - 1) * plane, L2h,
        XS + (size_t)(k >= 2 ? k - 2 : 0) * plane, XS + (size_t)k * plane,
        1024, (k == 1) ? 1.f : 2.f, (k == 1) ? 0.f : 1.f);
  }
  k_dense<<<dim3(512, 2), 256, 0, stream>>>(W2p, XS, b2, Yt, 1024, 6, 52, plane,
                                            32768, 1.f, 0.015625f);
  k_pool2<<<4096, 256, 0, stream>>>(Yt, p2);
  k_fc_part<<<256, 256, 0, stream>>>(p2, Wfc, partF);
  k_fc_final<<<1, 320, 0, stream>>>(partF, bfc, out);
}

// Round 4
// 1202.039 us; speedup vs baseline: 1.4331x; 1.0754x over previous
//
#include <hip/hip_runtime.h>

typedef _Float16 half8 __attribute__((ext_vector_type(8)));
typedef _Float16 half4 __attribute__((ext_vector_type(4)));
typedef float f32x4 __attribute__((ext_vector_type(4)));

__device__ __forceinline__ void gload_lds16(const void* g, void* l) {
  __builtin_amdgcn_global_load_lds((const __attribute__((address_space(1))) void*)g,
                                   (__attribute__((address_space(3))) void*)l, 16, 0, 0);
}

// ---------------- BN partial sums: grid 128 = (seg<<4 | c) ----------------
__global__ __launch_bounds__(256) void k_bn_partial(const float* __restrict__ x,
                                                    float* __restrict__ part) {
  const int c = blockIdx.x & 15;
  const int seg = blockIdx.x >> 4;  // 0..7, 500 vertices each
  const int t = threadIdx.x;
  float s = 0.f, s2 = 0.f;
  for (int b = 0; b < 32; ++b) {
    const float* row = x + (size_t)(b * 16 + c) * 4000 + seg * 500;
    for (int v = t; v < 500; v += 256) {
      float val = row[v];
      s += val;
      s2 += val * val;
    }
  }
#pragma unroll
  for (int off = 32; off > 0; off >>= 1) {
    s += __shfl_down(s, off);
    s2 += __shfl_down(s2, off);
  }
  __shared__ float rs_[4], rs2_[4];
  if ((t & 63) == 0) { rs_[t >> 6] = s; rs2_[t >> 6] = s2; }
  __syncthreads();
  if (t == 0) {
    part[c * 8 + seg] = rs_[0] + rs_[1] + rs_[2] + rs_[3];
    part[128 + c * 8 + seg] = rs2_[0] + rs2_[1] + rs2_[2] + rs2_[3];
  }
}

// ---------------- BN finalize: musig[c]=mu, musig[16+c]=rstd ----------------
__global__ void k_bn_final(const float* __restrict__ part, float* __restrict__ musig) {
  const int c = threadIdx.x;
  if (c < 16) {
    float S = 0.f, S2 = 0.f;
#pragma unroll
    for (int seg = 0; seg < 8; ++seg) {
      S += part[c * 8 + seg];
      S2 += part[128 + c * 8 + seg];
    }
    const float inv = 1.f / 128000.f;
    float mu = S * inv;
    float var = S2 * inv - mu * mu;
    musig[c] = mu;
    musig[16 + c] = rsqrtf(var + 1e-5f);
  }
}

// ---------------- build x0 (normalized, permuted, transposed, scaled 1/16) ----------------
__global__ __launch_bounds__(256) void k_build_x0(const float* __restrict__ x,
                                                  const int* __restrict__ perm,
                                                  const float* __restrict__ musig,
                                                  _Float16* __restrict__ X0) {
  const int idx = blockIdx.x * 256 + threadIdx.x;  // < 512*4096
  const int v = idx & 4095;
  const int m = idx >> 12;
  const int b = m & 31;
  const int c = m >> 5;
  const int pv = perm[v];
  float val = 0.f;
  if (pv < 4000)
    val = (x[((size_t)(b * 16 + c)) * 4000 + pv] - musig[c]) * musig[16 + c] * 0.0625f;
  X0[idx] = (_Float16)val;
}

// ---------------- f32 -> f16 convert ----------------
__global__ __launch_bounds__(256) void k_cvt_f16(const float* __restrict__ s,
                                                 _Float16* __restrict__ d, int n) {
  const int i = (blockIdx.x * 256 + threadIdx.x) * 4;
  if (i >= n) return;
  f32x4 v = *(const f32x4*)(s + i);
  half4 h;
  h[0] = (_Float16)v[0]; h[1] = (_Float16)v[1];
  h[2] = (_Float16)v[2]; h[3] = (_Float16)v[3];
  *(half4*)(d + i) = h;
}

// ---------------- W permute+pad: Wp[f][k*CS + c] = W[f][c*25 + k], k<25 else 0 ----------------
__global__ __launch_bounds__(256) void k_prep_w(const float* __restrict__ W,
                                                _Float16* __restrict__ Wp,
                                                int F, int shiftC, int kround) {
  const int idx = blockIdx.x * 256 + threadIdx.x;
  const int CS = 1 << shiftC;
  const int KPtot = kround * CS;
  if (idx >= F * KPtot) return;
  const int f = idx / KPtot;
  const int rem = idx - f * KPtot;
  const int k = rem >> shiftC;
  const int c = rem & (CS - 1);
  float v = 0.f;
  if (k < 25) v = W[(size_t)f * (CS * 25) + c * 25 + k];
  Wp[idx] = (_Float16)v;
}

// ---------------- Chebyshev conv1 GEMM, cross-block K-split-4 ----------------
// P[kq][m][v] = sum_{u in kq-slice} Xprev[m][u] * L[v][u]
// Block: m=128 x v=256, K-slice 1024. 512 thr = 8 waves (2m x 4v), wave 64x64.
// bid: bx = bid&15 (v), by = (bid>>4)&3 (m), kq = bid>>6. XCD gets bx{x,x+8}.
__global__ __launch_bounds__(512, 1) void k_cheb_ks(const _Float16* __restrict__ Xprev,
                                                    const _Float16* __restrict__ Lm,
                                                    _Float16* __restrict__ P) {
  __shared__ _Float16 lds[2][24576];  // [buf][A:128x64 | B:256x64] = 96 KB
  const int t = threadIdx.x;
  const int lane = t & 63;
  const int w = t >> 6;
  const int wm = w >> 2, wn = w & 3;
  const int bid = blockIdx.x;
  const int bx = bid & 15;
  const int by = (bid >> 4) & 3;
  const int kq = bid >> 6;
  const int v0 = bx * 256, m0 = by * 128;
  const size_t rs = 8192;  // 4096 * 2 bytes

  const char* Ag = (const char*)Xprev + (size_t)m0 * rs + (size_t)kq * 2048;
  const char* Bg = (const char*)Lm + (size_t)v0 * rs + (size_t)kq * 2048;
  const size_t soff = (size_t)(lane >> 3) * rs + (size_t)(((lane & 7) * 16) ^ ((lane >> 3) << 4));

  f32x4 acc[4][4] = {};

  auto stage = [&](int buf, int tt) {  // 6 gload_lds per wave
    const char* ag = Ag + (size_t)tt * 128 + soff;
    const char* bg = Bg + (size_t)tt * 128 + soff;
    char* A = (char*)&lds[buf][0];
    char* B = (char*)&lds[buf][8192];
#pragma unroll
    for (int j = 0; j < 2; ++j) {  // A rows w*16 .. +15
      const int r0 = w * 16 + j * 8;
      gload_lds16(ag + (size_t)r0 * rs, A + r0 * 128);
    }
#pragma unroll
    for (int j = 0; j < 4; ++j) {  // B rows w*32 .. +31
      const int r0 = w * 32 + j * 8;
      gload_lds16(bg + (size_t)r0 * rs, B + r0 * 128);
    }
  };

  stage(0, 0);

  const int NT = 16;  // 1024 / 64
  for (int tt = 0; tt < NT; ++tt) {
    const int cur = tt & 1;
    if (tt + 1 < NT) {
      stage(cur ^ 1, tt + 1);
      asm volatile("s_waitcnt vmcnt(6)" ::: "memory");
    } else {
      asm volatile("s_waitcnt vmcnt(0)" ::: "memory");
    }
    asm volatile("s_barrier" ::: "memory");
    const char* A = (const char*)&lds[cur][0];
    const char* B = (const char*)&lds[cur][8192];
#pragma unroll
    for (int kk = 0; kk < 2; ++kk) {
      const int cb = kk * 64 + ((lane >> 4) << 4);
      half8 a[4], b[4];
#pragma unroll
      for (int mi = 0; mi < 4; ++mi) {
        const int ar = wm * 64 + mi * 16 + (lane & 15);
        a[mi] = *(const half8*)(A + ar * 128 + (cb ^ ((ar & 7) << 4)));
      }
#pragma unroll
      for (int ni = 0; ni < 4; ++ni) {
        const int br = wn * 64 + ni * 16 + (lane & 15);
        b[ni] = *(const half8*)(B + br * 128 + (cb ^ ((br & 7) << 4)));
      }
#pragma unroll
      for (int mi = 0; mi < 4; ++mi)
#pragma unroll
        for (int ni = 0; ni < 4; ++ni)
          acc[mi][ni] = __builtin_amdgcn_mfma_f32_16x16x32_f16(a[mi], b[ni], acc[mi][ni], 0, 0, 0);
    }
    asm volatile("s_barrier" ::: "memory");
  }

  _Float16* Pq = P + (size_t)kq * 2097152;
  const int rbase = (lane >> 4) << 2;
#pragma unroll
  for (int mi = 0; mi < 4; ++mi) {
#pragma unroll
    for (int ni = 0; ni < 4; ++ni) {
      const int vv = v0 + wn * 64 + ni * 16 + (lane & 15);
#pragma unroll
      for (int r = 0; r < 4; ++r) {
        const int mm = m0 + wm * 64 + mi * 16 + rbase + r;
        Pq[(size_t)mm * 4096 + vv] = (_Float16)acc[mi][ni][r];
      }
    }
  }
}

// ---------------- reduce partials: Xout = alpha*(P0+P1+P2+P3) - beta*Xm2 ----------------
__global__ __launch_bounds__(256) void k_cheb_red(const _Float16* __restrict__ P,
                                                  const _Float16* __restrict__ Xm2,
                                                  _Float16* __restrict__ Xout,
                                                  float alpha, float beta) {
  const int i = (blockIdx.x * 256 + threadIdx.x) * 8;
  half8 p0 = *(const half8*)(P + i);
  half8 p1 = *(const half8*)(P + 2097152 + i);
  half8 p2 = *(const half8*)(P + 4194304 + i);
  half8 p3 = *(const half8*)(P + 6291456 + i);
  half8 xm2 = {};
  if (beta != 0.f) xm2 = *(const half8*)(Xm2 + i);
  half8 o;
#pragma unroll
  for (int j = 0; j < 8; ++j) {
    float s = (float)p0[j] + (float)p1[j] + (float)p2[j] + (float)p3[j];
    o[j] = (_Float16)(alpha * s - beta * (float)xm2[j]);
  }
  *(half8*)(Xout + i) = o;
}

// ---------------- Chebyshev conv2 GEMM (R3 structure, in-block K-split-2) ----------------
__global__ __launch_bounds__(512, 2) void k_cheb(const _Float16* __restrict__ Xprev,
                                                 const _Float16* __restrict__ Lm,
                                                 const _Float16* __restrict__ Xm2,
                                                 _Float16* __restrict__ Xout,
                                                 int V, float alpha, float beta) {
  __shared__ _Float16 lds[2][2][12288];  // [kh][buf][A:128x64 | B:64x64]
  const int t = threadIdx.x;
  const int lane = t & 63;
  const int w = t >> 6;
  const int kh = w >> 2;
  const int wl = w & 3;
  const int wr = wl >> 1, wc = wl & 1;
  const int v0 = blockIdx.x * 64;
  const int m0 = blockIdx.y * 128;
  const size_t rs = (size_t)V * 2;
  const int K2 = V >> 1;
  const int NT2 = K2 >> 6;

  const char* Ag = (const char*)Xprev + (size_t)m0 * rs + (size_t)kh * K2 * 2;
  const char* Bg = (const char*)Lm + (size_t)v0 * rs + (size_t)kh * K2 * 2;
  const size_t soff = (size_t)(lane >> 3) * rs + (size_t)(((lane & 7) * 16) ^ ((lane >> 3) << 4));

  f32x4 acc[4][2] = {};

  auto stage = [&](int buf, int tt) {
    const char* ag = Ag + (size_t)tt * 128 + soff;
    const char* bg = Bg + (size_t)tt * 128 + soff;
    char* A = (char*)&lds[kh][buf][0];
    char* B = (char*)&lds[kh][buf][8192];
#pragma unroll
    for (int j = 0; j < 4; ++j) {
      const int r0 = wl * 32 + j * 8;
      gload_lds16(ag + (size_t)r0 * rs, A + r0 * 128);
    }
#pragma unroll
    for (int j = 0; j < 2; ++j) {
      const int r0 = wl * 16 + j * 8;
      gload_lds16(bg + (size_t)r0 * rs, B + r0 * 128);
    }
  };

  stage(0, 0);

  for (int tt = 0; tt < NT2; ++tt) {
    const int cur = tt & 1;
    if (tt + 1 < NT2) {
      stage(cur ^ 1, tt + 1);
      asm volatile("s_waitcnt vmcnt(6)" ::: "memory");
    } else {
      asm volatile("s_waitcnt vmcnt(0)" ::: "memory");
    }
    asm volatile("s_barrier" ::: "memory");
    const char* A = (const char*)&lds[kh][cur][0];
    const char* B = (const char*)&lds[kh][cur][8192];
#pragma unroll
    for (int kk = 0; kk < 2; ++kk) {
      const int cb = kk * 64 + ((lane >> 4) << 4);
      half8 a[4], b[2];
#pragma unroll
      for (int mi = 0; mi < 4; ++mi) {
        const int ar = wr * 64 + mi * 16 + (lane & 15);
        a[mi] = *(const half8*)(A + ar * 128 + (cb ^ ((ar & 7) << 4)));
      }
#pragma unroll
      for (int ni = 0; ni < 2; ++ni) {
        const int br = wc * 32 + ni * 16 + (lane & 15);
        b[ni] = *(const half8*)(B + br * 128 + (cb ^ ((br & 7) << 4)));
      }
#pragma unroll
      for (int mi = 0; mi < 4; ++mi)
#pragma unroll
        for (int ni = 0; ni < 2; ++ni)
          acc[mi][ni] = __builtin_amdgcn_mfma_f32_16x16x32_f16(a[mi], b[ni], acc[mi][ni], 0, 0, 0);
    }
    asm volatile("s_barrier" ::: "memory");
  }

  __syncthreads();
  float* red = (float*)&lds[0][0][0];
  if (kh == 1) {
    float* dst = red + wl * 2048 + lane * 4;
#pragma unroll
    for (int mi = 0; mi < 4; ++mi)
#pragma unroll
      for (int ni = 0; ni < 2; ++ni)
        *(f32x4*)(dst + (mi * 2 + ni) * 256) = acc[mi][ni];
  }
  __syncthreads();
  if (kh == 0) {
    const float* src = red + wl * 2048 + lane * 4;
    const int rbase = (lane >> 4) << 2;
#pragma unroll
    for (int mi = 0; mi < 4; ++mi) {
#pragma unroll
      for (int ni = 0; ni < 2; ++ni) {
        f32x4 o = *(const f32x4*)(src + (mi * 2 + ni) * 256);
        const int vv = v0 + wc * 32 + ni * 16 + (lane & 15);
#pragma unroll
        for (int r = 0; r < 4; ++r) {
          const int mm = m0 + wr * 64 + mi * 16 + rbase + r;
          const size_t idx = (size_t)mm * V + vv;
          float val = alpha * (acc[mi][ni][r] + o[r]);
          if (beta != 0.f) val -= (float)Xm2[idx];
          Xout[idx] = (_Float16)val;
        }
      }
    }
  }
}

// ---------------- Dense projection GEMM (64f x 64n tile), fused bias+relu ----------------
// A rows padded to 80B (b128-aligned, ~2-way banks); B rows padded to 132B
// (33-dword stride -> conflict-free u16 gather).
__global__ __launch_bounds__(256, 2) void k_dense(const _Float16* __restrict__ Wp,
                                                  const _Float16* __restrict__ XS,
                                                  const float* __restrict__ bias,
                                                  float* __restrict__ Yt,
                                                  int Vv, int shiftC, int nsteps,
                                                  size_t planeV, int Ntot,
                                                  float ascale, float bscale) {
  __shared__ _Float16 Alds[64 * 40];  // 80B rows
  __shared__ _Float16 Blds[32 * 66];  // 132B rows
  const int t = threadIdx.x;
  const int lane = t & 63;
  const int w = t >> 6;
  const int n0 = blockIdx.x * 64;
  const int f0 = blockIdx.y * 64;
  const int b = n0 / Vv;
  const int vb = n0 % Vv;
  const int KP = nsteps * 32;
  const int cmask = (1 << shiftC) - 1;

  f32x4 acc0 = {0.f, 0.f, 0.f, 0.f}, acc1 = {0.f, 0.f, 0.f, 0.f};
  f32x4 acc2 = {0.f, 0.f, 0.f, 0.f}, acc3 = {0.f, 0.f, 0.f, 0.f};

  for (int s = 0; s < nsteps; ++s) {
    const int q0 = s * 32;
    {  // A stage: 64 rows x 64B -> 80B-strided
      const int row = t >> 2, cb = (t & 3) * 16;
      half8 v = *(const half8*)((const char*)Wp + ((size_t)(f0 + row) * KP + q0) * 2 + cb);
      *(half8*)((char*)Alds + row * 80 + cb) = v;
    }
    {  // B stage: 32 rows x 128B -> 132B-strided (4x b32 writes), zero-pad k>=25
      const int q = q0 + (t >> 3), cb = (t & 7) * 16;
      const int k = q >> shiftC, c = q & cmask;
      half8 v = {};
      if (k < 25)
        v = *(const half8*)((const char*)XS +
                            ((size_t)k * planeV + (size_t)(c * 32 + b) * Vv + vb) * 2 + cb);
      uint4 uv = *(uint4*)&v;
      uint* ud = (uint*)((char*)Blds + (t >> 3) * 132 + cb);
      ud[0] = uv.x; ud[1] = uv.y; ud[2] = uv.z; ud[3] = uv.w;
    }
    __syncthreads();
    const int g16 = (lane >> 4) << 4;
    half8 a0 = *(const half8*)((char*)Alds + ((lane & 15) + 0) * 80 + g16);
    half8 a1 = *(const half8*)((char*)Alds + ((lane & 15) + 16) * 80 + g16);
    half8 a2 = *(const half8*)((char*)Alds + ((lane & 15) + 32) * 80 + g16);
    half8 a3 = *(const half8*)((char*)Alds + ((lane & 15) + 48) * 80 + g16);
    half8 bf;
    const int col = (w << 4) + (lane & 15);
#pragma unroll
    for (int j = 0; j < 8; ++j)
      bf[j] = Blds[(((lane >> 4) << 3) + j) * 66 + col];
    acc0 = __builtin_amdgcn_mfma_f32_16x16x32_f16(a0, bf, acc0, 0, 0, 0);
    acc1 = __builtin_amdgcn_mfma_f32_16x16x32_f16(a1, bf, acc1, 0, 0, 0);
    acc2 = __builtin_amdgcn_mfma_f32_16x16x32_f16(a2, bf, acc2, 0, 0, 0);
    acc3 = __builtin_amdgcn_mfma_f32_16x16x32_f16(a3, bf, acc3, 0, 0, 0);
    __syncthreads();
  }

  const int n = n0 + (w << 4) + (lane & 15);
  f32x4 accs[4] = {acc0, acc1, acc2, acc3};
#pragma unroll
  for (int mi = 0; mi < 4; ++mi) {
#pragma unroll
    for (int r = 0; r < 4; ++r) {
      const int f = f0 + (mi << 4) + ((lane >> 4) << 2) + r;
      float val = ascale * accs[mi][r] + bscale * bias[f];
      Yt[(size_t)f * Ntot + n] = fmaxf(val, 0.f);
    }
  }
}

// ---------------- pool1: Yt1(64 x 131072) -> XS plane0 (2048 x 1024), scale 1/64 ----------------
__global__ __launch_bounds__(256) void k_pool1(const float* __restrict__ Yt,
                                               _Float16* __restrict__ X2) {
  const int idx = blockIdx.x * 256 + threadIdx.x;  // < 64*32*1024
  const int v2 = idx & 1023;
  const int rest = idx >> 10;
  const int b = rest & 31;
  const int f = rest >> 5;
  f32x4 q = *(const f32x4*)(Yt + (size_t)f * 131072 + b * 4096 + v2 * 4);
  float mx = fmaxf(fmaxf(q[0], q[1]), fmaxf(q[2], q[3]));
  X2[(size_t)(f * 32 + b) * 1024 + v2] = (_Float16)(mx * 0.015625f);
}

// ---------------- pool2: Yt2(128 x 32768) -> p2[b][f][v3] (32 x 128 x 256) ----------------
__global__ __launch_bounds__(256) void k_pool2(const float* __restrict__ Yt,
                                               float* __restrict__ p2) {
  const int idx = blockIdx.x * 256 + threadIdx.x;  // < 32*128*256
  const int v3 = idx & 255;
  const int rest = idx >> 8;
  const int f = rest & 127;
  const int b = rest >> 7;
  f32x4 q = *(const f32x4*)(Yt + (size_t)f * 32768 + b * 1024 + v3 * 4);
  float mx = fmaxf(fmaxf(q[0], q[1]), fmaxf(q[2], q[3]));
  p2[(size_t)b * 32768 + f * 256 + v3] = mx;
}

// ---------------- FC pass 1: partial GEMV, grid 256 = (b<<3 | seg) ----------------
__global__ __launch_bounds__(256) void k_fc_part(const float* __restrict__ p2,
                                                 const float* __restrict__ Wfc,
                                                 float* __restrict__ partF) {
  const int b = blockIdx.x >> 3;
  const int seg = blockIdx.x & 7;
  const int t = threadIdx.x;
  const int lane = t & 63;
  const int w = t >> 6;
  const int base = seg * 4096;
  float acc[10];
#pragma unroll
  for (int o = 0; o < 10; ++o) acc[o] = 0.f;
  const float* pb = p2 + (size_t)b * 32768 + base;
  for (int i = t; i < 4096; i += 256) {
    float p = pb[i];
#pragma unroll
    for (int o = 0; o < 10; ++o) acc[o] += p * Wfc[(size_t)o * 32768 + base + i];
  }
#pragma unroll
  for (int off = 32; off > 0; off >>= 1)
#pragma unroll
    for (int o = 0; o < 10; ++o) acc[o] += __shfl_down(acc[o], off);
  __shared__ float rws[10][4];
  if (lane == 0) {
#pragma unroll
    for (int o = 0; o < 10; ++o) rws[o][w] = acc[o];
  }
  __syncthreads();
  if (t < 10) partF[blockIdx.x * 10 + t] =
      rws[t][0] + rws[t][1] + rws[t][2] + rws[t][3];
}

// ---------------- FC pass 2 ----------------
__global__ void k_fc_final(const float* __restrict__ partF,
                           const float* __restrict__ bfc,
                           float* __restrict__ out) {
  const int t = threadIdx.x;
  if (t < 320) {
    const int b = t / 10, o = t - b * 10;
    float s = 0.f;
#pragma unroll
    for (int seg = 0; seg < 8; ++seg) s += partF[(b * 8 + seg) * 10 + o];
    out[b * 10 + o] = 64.f * s + bfc[o];
  }
}

extern "C" void kernel_launch(void* const* d_in, const int* in_sizes, int n_in,
                              void* d_out, int out_size, void* d_ws, size_t ws_size,
                              hipStream_t stream) {
  (void)in_sizes; (void)n_in; (void)out_size; (void)ws_size;
  const float* x = (const float*)d_in[0];
  const int* perm = (const int*)d_in[1];
  const float* L1 = (const float*)d_in[2];
  const float* L2 = (const float*)d_in[3];
  const float* W1 = (const float*)d_in[4];
  const float* b1 = (const float*)d_in[5];
  const float* W2 = (const float*)d_in[6];
  const float* b2 = (const float*)d_in[7];
  const float* Wfc = (const float*)d_in[8];
  const float* bfc = (const float*)d_in[9];
  float* out = (float*)d_out;

  char* ws = (char*)d_ws;
  size_t off = 0;
  auto alloc = [&](size_t bytes) {
    char* p = ws + off;
    off += (bytes + 255) & ~(size_t)255;
    return p;
  };
  _Float16* L1h = (_Float16*)alloc(16777216ull * 2);
  _Float16* L2h = (_Float16*)alloc(1048576ull * 2);
  _Float16* W1p = (_Float16*)alloc(64ull * 448 * 2);
  _Float16* W2p = (_Float16*)alloc(128ull * 1664 * 2);
  float* part = (float*)alloc(256 * 4);
  float* musig = (float*)alloc(32 * 4);
  float* partF = (float*)alloc(2560 * 4);
  _Float16* XS = (_Float16*)alloc(25ull * 2097152 * 2);   // states
  _Float16* Pq = (_Float16*)alloc(4ull * 2097152 * 2);    // K-split partials
  float* Yt = (float*)alloc(64ull * 131072 * 4);
  float* p2 = (float*)alloc(32ull * 128 * 256 * 4);

  k_cvt_f16<<<16384, 256, 0, stream>>>(L1, L1h, 16777216);
  k_cvt_f16<<<1024, 256, 0, stream>>>(L2, L2h, 1048576);
  k_prep_w<<<112, 256, 0, stream>>>(W1, W1p, 64, 4, 28);
  k_prep_w<<<832, 256, 0, stream>>>(W2, W2p, 128, 6, 26);
  k_bn_partial<<<128, 256, 0, stream>>>(x, part);
  k_bn_final<<<1, 64, 0, stream>>>(part, musig);
  k_build_x0<<<8192, 256, 0, stream>>>(x, perm, musig, XS);

  const size_t plane = 2097152;
  for (int k = 1; k < 25; ++k) {
    k_cheb_ks<<<256, 512, 0, stream>>>(XS + (size_t)(k - 1) * plane, L1h, Pq);
    k_cheb_red<<<1024, 256, 0, stream>>>(
        Pq, XS + (size_t)(k >= 2 ? k - 2 : 0) * plane, XS + (size_t)k * plane,
        (k == 1) ? 1.f : 2.f, (k == 1) ? 0.f : 1.f);
  }
  k_dense<<<dim3(2048, 1), 256, 0, stream>>>(W1p, XS, b1, Yt, 4096, 4, 14, plane,
                                             131072, 16.f, 1.f);
  k_pool1<<<8192, 256, 0, stream>>>(Yt, XS);
  for (int k = 1; k < 25; ++k) {
    k_cheb<<<dim3(16, 16), 512, 0, stream>>>(
        XS + (size_t)(k - 1) * plane, L2h,
        XS + (size_t)(k >= 2 ? k - 2 : 0) * plane, XS + (size_t)k * plane,
        1024, (k == 1) ? 1.f : 2.f, (k == 1) ? 0.f : 1.f);
  }
  k_dense<<<dim3(512, 2), 256, 0, stream>>>(W2p, XS, b2, Yt, 1024, 6, 52, plane,
                                            32768, 1.f, 0.015625f);
  k_pool2<<<4096, 256, 0, stream>>>(Yt, p2);
  k_fc_part<<<256, 256, 0, stream>>>(p2, Wfc, partF);
  k_fc_final<<<1, 320, 0, stream>>>(partF, bfc, out);
}